// Round 13
// baseline (323.722 us; speedup 1.0000x reference)
//
#include <hip/hip_runtime.h>

#define B_  2
#define S_  2048
#define D_  1024
#define H_  16
#define HD_ 64
#define M_  (B_*S_)   // 4096 tokens

typedef __bf16 bf16_t;
typedef __bf16 bf16x8 __attribute__((ext_vector_type(8)));
typedef float  f32x4  __attribute__((ext_vector_type(4)));
typedef short  s16x4  __attribute__((ext_vector_type(4)));

union U16x8 { uint4 u; bf16x8 v; };
union U16x4 { uint2 u; bf16_t e[4]; };
union U16x4s { uint2 u; s16x4 s; bf16_t e[4]; };

__device__ __forceinline__ bf16x8 ld_frag(const bf16_t* p) {
    U16x8 t; t.u = *(const uint4*)p; return t.v;
}

// async global->LDS DMA, 16 B per lane. LDS dest must be wave-uniform base;
// HW adds lane*16. Global src is per-lane.
__device__ __forceinline__ void gload16(const bf16_t* g, bf16_t* l) {
    __builtin_amdgcn_global_load_lds(
        (const __attribute__((address_space(1))) unsigned int*)g,
        (__attribute__((address_space(3))) unsigned int*)l,
        16, 0, 0);
}

// ---------------------------------------------------------------------------
// Ingestion, one launch. grid (32,32,5), block (32,8):
//   z<4 : weight fp32 [1024][1024] -> bf16 transposed [n][k] (z selects W)
//   z==4: x fp32 -> bf16, 16 elems/thread (1024 block-slots x 4096 elems)
// ---------------------------------------------------------------------------
__global__ __launch_bounds__(256) void ingest(const float* __restrict__ w0,
                                              const float* __restrict__ w1,
                                              const float* __restrict__ w2,
                                              const float* __restrict__ w3,
                                              const float* __restrict__ xin,
                                              bf16_t* __restrict__ wtout,
                                              bf16_t* __restrict__ xout) {
    const int RC = 1024;
    int z = blockIdx.z;
    if (z == 4) {
        int bid = blockIdx.y * 32 + blockIdx.x;
        int t = threadIdx.y * 32 + threadIdx.x;
        int i = bid * 4096 + t * 16;
#pragma unroll
        for (int g = 0; g < 2; g++) {
            float4 a = *(const float4*)(xin + i + g * 8);
            float4 b = *(const float4*)(xin + i + g * 8 + 4);
            bf16_t o[8] = {(bf16_t)a.x, (bf16_t)a.y, (bf16_t)a.z, (bf16_t)a.w,
                           (bf16_t)b.x, (bf16_t)b.y, (bf16_t)b.z, (bf16_t)b.w};
            *(uint4*)(xout + i + g * 8) = *(uint4*)o;
        }
        return;
    }
    __shared__ bf16_t tile[32][33];
    const float* in = (z == 0) ? w0 : (z == 1) ? w1 : (z == 2) ? w2 : w3;
    bf16_t* out = wtout + (size_t)z * RC * RC;
    int c0 = blockIdx.x * 32, r0 = blockIdx.y * 32;
    int tx = threadIdx.x, ty = threadIdx.y;
#pragma unroll
    for (int i = 0; i < 32; i += 8)
        tile[ty + i][tx] = (bf16_t)in[(size_t)(r0 + ty + i) * RC + c0 + tx];
    __syncthreads();
#pragma unroll
    for (int i = 0; i < 32; i += 8)
        out[(size_t)(c0 + ty + i) * RC + r0 + tx] = tile[tx][ty + i];
}

// ===========================================================================
// GEMM core, 128x128 tile, 4 waves (2x2), wave 64x64 via 4x4
// mfma_f32_16x16x32_bf16, BK=64, global_load_lds width-16 into [128][64]
// LDS, 2 buffers, T4 counted-vmcnt pipeline (never vmcnt(0) in steady state).
// T2 both-sides swizzle (r7: conflict 9.5M -> gone; element (row,c) lives at
// phys col c ^ ((row&7)*8); source col pre-inverse-swizzled, read XORs).
// Pipeline: prologue issues tile0->buf0, tile1->buf1; step i: vmcnt(8) ->
// s_barrier -> MFMA -> lgkmcnt(0) -> s_barrier -> issue tile i+2.
// Raw s_barrier, NOT __syncthreads (that drains vmcnt(0) = the stall).
// 64 KB LDS -> 2 blocks/CU.
// Epilogue may reuse smem (32768 elems) as a [128][136] transpose buffer.
// ===========================================================================
#define STAGE_TILE(A_, Wt_, koff, buf)                                        \
    _Pragma("unroll") for (int c = 0; c < 4; c++) {                           \
        int rb = c * 32 + wid * 8;                                            \
        gload16(A_  + arow + (size_t)rb * K + (koff), (buf) + rb * 64);       \
        gload16(Wt_ + brow + (size_t)rb * K + (koff), (buf) + 8192 + rb * 64);\
    }

#define GEMM_CORE(A_, Wt_)                                                    \
    const int K = 1024;                                                       \
    __shared__ __align__(16) bf16_t smem[32768];                              \
    int t = threadIdx.x;                                                      \
    int wid = t >> 6, lane = t & 63, ln = lane & 15, quad = lane >> 4;        \
    int wm = (wid >> 1) * 64, wn = (wid & 1) * 64;                            \
    f32x4 zero = {0.f, 0.f, 0.f, 0.f};                                        \
    f32x4 acc[4][4];                                                          \
    _Pragma("unroll") for (int i = 0; i < 4; i++)                             \
        _Pragma("unroll") for (int j = 0; j < 4; j++) acc[i][j] = zero;       \
    int sr8 = lane >> 3;                                                      \
    int scs = (((lane & 7) ^ sr8) * 8);      /* swizzled source col */        \
    int swr = (ln & 7) * 8;                  /* read-side XOR key   */        \
    const size_t arow = (size_t)(m0 + sr8) * K + scs;                         \
    const size_t brow = (size_t)(n0 + sr8) * K + scs;                         \
    STAGE_TILE(A_, Wt_, 0, smem)                                              \
    STAGE_TILE(A_, Wt_, 64, smem + 16384)                                     \
    for (int it = 0; it < 16; it++) {                                         \
        if (it < 15) asm volatile("s_waitcnt vmcnt(8)" ::: "memory");         \
        else         asm volatile("s_waitcnt vmcnt(0)" ::: "memory");         \
        __builtin_amdgcn_sched_barrier(0);                                    \
        __builtin_amdgcn_s_barrier();                                         \
        bf16_t* a_lds = smem + (it & 1) * 16384;                              \
        bf16_t* b_lds = a_lds + 8192;                                         \
        _Pragma("unroll") for (int ks = 0; ks < 2; ks++) {                    \
            bf16x8 af[4], bfr[4];                                             \
            _Pragma("unroll") for (int i = 0; i < 4; i++)                     \
                af[i] = ld_frag(a_lds + (wm + i * 16 + ln) * 64 +             \
                                ((ks * 32 + quad * 8) ^ swr));                \
            _Pragma("unroll") for (int j = 0; j < 4; j++)                     \
                bfr[j] = ld_frag(b_lds + (wn + j * 16 + ln) * 64 +            \
                                 ((ks * 32 + quad * 8) ^ swr));               \
            _Pragma("unroll") for (int i = 0; i < 4; i++)                     \
                _Pragma("unroll") for (int j = 0; j < 4; j++)                 \
                    acc[i][j] = __builtin_amdgcn_mfma_f32_16x16x32_bf16(      \
                        af[i], bfr[j], acc[i][j], 0, 0, 0);                   \
        }                                                                     \
        asm volatile("s_waitcnt lgkmcnt(0)" ::: "memory");                    \
        __builtin_amdgcn_sched_barrier(0);                                    \
        __builtin_amdgcn_s_barrier();                                        \
        if (it < 14) {                                                        \
            int koff = (it + 2) * 64;                                         \
            bf16_t* bufn = smem + (it & 1) * 16384;                           \
            STAGE_TILE(A_, Wt_, koff, bufn)                                   \
        }                                                                     \
    }

// ---------------------------------------------------------------------------
// Fused QKV projection. grid (24, 32): bx>>3 selects {Q,K,V}, n0=(bx&7)*128.
// Wt buffers contiguous at wtbase (+wsel*1M); outputs contiguous at outbase
// (+wsel*4M). Q,K -> [B,H,S,HD]; V -> [B,H,HD,S] via LDS transpose epilogue.
// ---------------------------------------------------------------------------
__global__ __launch_bounds__(256) void gemm_qkv(const bf16_t* __restrict__ A,
                                                const bf16_t* __restrict__ wtbase,
                                                bf16_t* __restrict__ outbase) {
    int wsel = blockIdx.x >> 3;
    int n0 = (blockIdx.x & 7) * 128;
    int m0 = blockIdx.y * 128;
    const bf16_t* Wt = wtbase + (size_t)wsel * 1024 * 1024;
    bf16_t* out = outbase + (size_t)wsel * 4 * 1024 * 1024;

    GEMM_CORE(A, Wt)

    if (wsel < 2) {
        // C[m][n] -> out[b][h][s][hd]  (32-B quad chunks, lines complete in j-loop)
#pragma unroll
        for (int i = 0; i < 4; i++)
#pragma unroll
            for (int j = 0; j < 4; j++) {
                int n = n0 + wn + j * 16 + ln;
                int h = n >> 6, hd = n & 63;
#pragma unroll
                for (int r = 0; r < 4; r++) {
                    int m = m0 + wm + i * 16 + quad * 4 + r;
                    int b = m >> 11, s = m & 2047;
                    out[(((size_t)(b * H_ + h) * S_ + s) * HD_) + hd] =
                        (bf16_t)acc[i][j][r];
                }
            }
    } else {
        // V: transpose C-tile in LDS, then write [b][h][hd][s] coalesced.
        // Loop ended with s_barrier after lgkmcnt(0): smem safely reusable.
        bf16_t* tr = smem;               // [128][136]  (17408 elems, fits)
#pragma unroll
        for (int i = 0; i < 4; i++)
#pragma unroll
            for (int j = 0; j < 4; j++) {
                U16x4 pk;                // acc[i][j][0..3] are consecutive m
#pragma unroll
                for (int r = 0; r < 4; r++) pk.e[r] = (bf16_t)acc[i][j][r];
                *(uint2*)(tr + (wn + j * 16 + ln) * 136 + wm + i * 16 + quad * 4) = pk.u;
            }
        __syncthreads();
        int row = t >> 1, half = t & 1;      // row = n-local, 2 thr/row
        int n = n0 + row;
        int h = n >> 6, hd = n & 63;
        int b = m0 >> 11, s0 = (m0 & 2047) + half * 64;
        const bf16_t* src = tr + row * 136 + half * 64;
        bf16_t* dst = out + (((size_t)(b * H_ + h) * HD_ + hd) * S_) + s0;
#pragma unroll
        for (int u = 0; u < 8; u++)
            *(uint4*)(dst + u * 8) = *(const uint4*)(src + u * 8);
    }
}

// ---------------------------------------------------------------------------
// Output projection: fp32 out[M][N] = ctx @ Wo + bo. grid (8, 32).
// ---------------------------------------------------------------------------
__global__ __launch_bounds__(256) void gemm_out(const bf16_t* __restrict__ A,
                                                const bf16_t* __restrict__ Wt,
                                                float* __restrict__ out,
                                                const float* __restrict__ bias) {
    const int N = 1024;
    int n0 = blockIdx.x * 128;
    int m0 = blockIdx.y * 128;

    GEMM_CORE(A, Wt)

#pragma unroll
    for (int i = 0; i < 4; i++)
#pragma unroll
        for (int j = 0; j < 4; j++) {
            int n = n0 + wn + j * 16 + ln;
            float bv = bias[n];
#pragma unroll
            for (int r = 0; r < 4; r++) {
                int m = m0 + wm + i * 16 + quad * 4 + r;
                out[(size_t)m * N + n] = acc[i][j][r] + bv;
            }
        }
}

// ---------------------------------------------------------------------------
// Causal flash attention, static-max softmax (M=16; scores bounded ~14.5).
// p = exp(s-16), l = deferred sum, O = MFMA(P,V); O/l exact at epilogue.
// Swapped QK^T + zero-shuffle PV (r8): sacc[tt]=mfma(K,Q) -> thread holds
// P[k][q=ln] registers that feed mfma_f32_16x16x16bf16_1k A-operand direct.
//
// r12 lesson: attn time is invariant (52-63us) across staging/barrier
// structures -> the staging+barrier coupling itself is the overhead, and
// K/V is L2-RESIDENT (FETCH 12MB, 2MB/XCD via bh grouping). This round:
// NO LDS, NO barriers -- every wave reads K and V fragments directly from
// global (L2 hit ~200cy, hidden by TLP). Removes per tile: 1 barrier,
// 4 ds_write_b128, 24 ds_reads, all bank conflicts, prefetch reg dance.
// Cost: 4x L2 read traffic (each wave reads the full 8KB K + 8KB V tile)
// ~= 1.08 GB @ 34.5 TB/s aggregate -- affordable. Occupancy now VGPR-bound
// only; waves fully independent.
//
// Grid 1024, balance by construction (r10/r11): xcd=bid&7, c=(bid>>3)&31,
// g=bid>>8; bh=xcd+8g (K/V L2-resident per XCD); qt=(g&1)?c:31-c (every
// CU's resident blocks sum to uniform KV-tile work).
// Causal mask only at kt==qt (wave-uniform branch).
// Q,K: [B*H][S][64] ; Vt: [B*H][64][S] ; ctx: [B][S][H*64] bf16
// ---------------------------------------------------------------------------
__global__ __launch_bounds__(256) void attn64(const bf16_t* __restrict__ Q,
                                              const bf16_t* __restrict__ Kg,
                                              const bf16_t* __restrict__ Vt,
                                              bf16_t* __restrict__ ctx) {
    int t = threadIdx.x;
    int wid = t >> 6, lane = t & 63, ln = lane & 15, quad = lane >> 4;

    int bid = blockIdx.x;                        // 1024 blocks
    int xcd = bid & 7;
    int c   = (bid >> 3) & 31;                   // CU-within-XCD (round robin)
    int g   = bid >> 8;                          // resident slot 0..3
    int bh  = xcd + (g << 3);
    int qt  = (g & 1) ? c : (31 - c);
    int b = bh >> 4, h = bh & 15;
    const bf16_t* Qb = Q  + (size_t)bh * S_ * HD_;
    const bf16_t* Kb = Kg + (size_t)bh * S_ * HD_;
    const bf16_t* Vb = Vt + (size_t)bh * HD_ * S_;

    f32x4 zero = {0.f, 0.f, 0.f, 0.f};

    int q0 = qt * 64;
    int nkt = qt + 1;

    int qrow = q0 + wid * 16 + ln;               // this thread's q (col idx)
    bf16x8 qf0 = ld_frag(Qb + (size_t)qrow * HD_ + quad * 8);
    bf16x8 qf1 = ld_frag(Qb + (size_t)qrow * HD_ + 32 + quad * 8);

    f32x4 oacc[4];
#pragma unroll
    for (int i = 0; i < 4; i++) oacc[i] = zero;
    float lsum = 0.f;                            // partial row-sum for q=qrow

    for (int kt = 0; kt < nkt; kt++) {
        // S^T = K Q^T : K fragments straight from global (L2-hot).
        // sacc[tt][r] = S[k=kt*64+tt*16+quad*4+r][q=qrow]
        f32x4 sacc[4];
#pragma unroll
        for (int tt = 0; tt < 4; tt++) sacc[tt] = zero;
#pragma unroll
        for (int tt = 0; tt < 4; tt++) {
            const bf16_t* krow = Kb + (size_t)(kt * 64 + tt * 16 + ln) * HD_;
            bf16x8 a0 = ld_frag(krow + quad * 8);
            bf16x8 a1 = ld_frag(krow + 32 + quad * 8);
            sacc[tt] = __builtin_amdgcn_mfma_f32_16x16x32_bf16(a0, qf0, sacc[tt], 0, 0, 0);
            sacc[tt] = __builtin_amdgcn_mfma_f32_16x16x32_bf16(a1, qf1, sacc[tt], 0, 0, 0);
        }

        U16x4s pa[4];
        if (kt == nkt - 1) {              // diagonal tile: mask k > q
#pragma unroll
            for (int tt = 0; tt < 4; tt++) {
#pragma unroll
                for (int r = 0; r < 4; r++) {
                    int kg = kt * 64 + tt * 16 + quad * 4 + r;
                    float pv = __expf(__builtin_fmaf((float)sacc[tt][r], 0.125f, -16.0f));
                    if (kg > qrow) pv = 0.f;
                    lsum += pv;
                    pa[tt].e[r] = (bf16_t)pv;
                }
            }
        } else {                          // interior tile: no mask
#pragma unroll
            for (int tt = 0; tt < 4; tt++) {
#pragma unroll
                for (int r = 0; r < 4; r++) {
                    float pv = __expf(__builtin_fmaf((float)sacc[tt][r], 0.125f, -16.0f));
                    lsum += pv;
                    pa[tt].e[r] = (bf16_t)pv;
                }
            }
        }

        // PV: P registers feed 16x16x16 MFMA A-operand directly; V B-frag
        // straight from global (uint2, 8B aligned, L2-hot).
#pragma unroll
        for (int th = 0; th < 4; th++) {
            const bf16_t* vrow = Vb + (size_t)(th * 16 + ln) * S_ + kt * 64;
#pragma unroll
            for (int tt = 0; tt < 4; tt++) {
                U16x4s vb;
                vb.u = *(const uint2*)(vrow + tt * 16 + quad * 4);
                oacc[th] = __builtin_amdgcn_mfma_f32_16x16x16bf16_1k(
                    pa[tt].s, vb.s, oacc[th], 0, 0, 0);
            }
        }
    }

    // l totals: sum the 4 quad-partials for each q=ln
    lsum += __shfl_xor(lsum, 16);
    lsum += __shfl_xor(lsum, 32);

#pragma unroll
    for (int r = 0; r < 4; r++) {
        int q = q0 + wid * 16 + quad * 4 + r;
        float inv = 1.f / __shfl(lsum, quad * 4 + r);  // lane q-local
#pragma unroll
        for (int th = 0; th < 4; th++) {
            int hd = h * 64 + th * 16 + ln;
            ctx[((size_t)(b * S_ + q)) * D_ + hd] = (bf16_t)(oacc[th][r] * inv);
        }
    }
}

// ---------------------------------------------------------------------------
extern "C" void kernel_launch(void* const* d_in, const int* in_sizes, int n_in,
                              void* d_out, int out_size, void* d_ws, size_t ws_size,
                              hipStream_t stream) {
    const float* x  = (const float*)d_in[0];
    const float* bo = (const float*)d_in[5];
    float* out = (float*)d_out;

    bf16_t* ws = (bf16_t*)d_ws;
    const size_t MM = 1024 * 1024;       // elements
    bf16_t* xb  = ws;                    // [M][D]  4 MM  (dead after QKV gemm)
    bf16_t* ctx = xb;                    //   alias — lifetimes disjoint
    bf16_t* wtq = xb + 4 * MM;           // [N][K]  1 MM each (q,k,v,o contig)
    bf16_t* wto = wtq + 3 * MM;
    bf16_t* qb  = wto + MM;              // [B,H,S,HD] 4 MM (q,k,vT contig)
    bf16_t* kb  = qb + 4 * MM;
    bf16_t* vtb = kb + 4 * MM;           // [B,H,HD,S]
    // total 20 MM elems = 40 MB

    ingest<<<dim3(32, 32, 5), dim3(32, 8, 1), 0, stream>>>(
        (const float*)d_in[1], (const float*)d_in[2],
        (const float*)d_in[3], (const float*)d_in[4], x, wtq, xb);

    gemm_qkv<<<dim3(24, 32, 1), 256, 0, stream>>>(xb, wtq, qb);

    attn64<<<1024, 256, 0, stream>>>(qb, kb, vtb, ctx);

    gemm_out<<<dim3(8, 32, 1), 256, 0, stream>>>(ctx, wto, out, bo);
}

// Round 14
// 195.429 us; speedup vs baseline: 1.6565x; 1.6565x over previous
//
#include <hip/hip_runtime.h>

#define B_  2
#define S_  2048
#define D_  1024
#define H_  16
#define HD_ 64
#define M_  (B_*S_)   // 4096 tokens

typedef __bf16 bf16_t;
typedef __bf16 bf16x8 __attribute__((ext_vector_type(8)));
typedef float  f32x4  __attribute__((ext_vector_type(4)));
typedef short  s16x4  __attribute__((ext_vector_type(4)));

union U16x8 { uint4 u; bf16x8 v; };
union U16x4 { uint2 u; bf16_t e[4]; };
union U16x4s { uint2 u; s16x4 s; bf16_t e[4]; };

__device__ __forceinline__ bf16x8 ld_frag(const bf16_t* p) {
    U16x8 t; t.u = *(const uint4*)p; return t.v;
}

// async global->LDS DMA, 16 B per lane. LDS dest must be wave-uniform base;
// HW adds lane*16. Global src is per-lane.
__device__ __forceinline__ void gload16(const bf16_t* g, bf16_t* l) {
    __builtin_amdgcn_global_load_lds(
        (const __attribute__((address_space(1))) unsigned int*)g,
        (__attribute__((address_space(3))) unsigned int*)l,
        16, 0, 0);
}

// ---------------------------------------------------------------------------
// Ingestion, one launch. grid (32,32,5), block (32,8):
//   z<4 : weight fp32 [1024][1024] -> bf16 transposed [n][k] (z selects W)
//   z==4: x fp32 -> bf16, 16 elems/thread (1024 block-slots x 4096 elems)
// ---------------------------------------------------------------------------
__global__ __launch_bounds__(256) void ingest(const float* __restrict__ w0,
                                              const float* __restrict__ w1,
                                              const float* __restrict__ w2,
                                              const float* __restrict__ w3,
                                              const float* __restrict__ xin,
                                              bf16_t* __restrict__ wtout,
                                              bf16_t* __restrict__ xout) {
    const int RC = 1024;
    int z = blockIdx.z;
    if (z == 4) {
        int bid = blockIdx.y * 32 + blockIdx.x;
        int t = threadIdx.y * 32 + threadIdx.x;
        int i = bid * 4096 + t * 16;
#pragma unroll
        for (int g = 0; g < 2; g++) {
            float4 a = *(const float4*)(xin + i + g * 8);
            float4 b = *(const float4*)(xin + i + g * 8 + 4);
            bf16_t o[8] = {(bf16_t)a.x, (bf16_t)a.y, (bf16_t)a.z, (bf16_t)a.w,
                           (bf16_t)b.x, (bf16_t)b.y, (bf16_t)b.z, (bf16_t)b.w};
            *(uint4*)(xout + i + g * 8) = *(uint4*)o;
        }
        return;
    }
    __shared__ bf16_t tile[32][33];
    const float* in = (z == 0) ? w0 : (z == 1) ? w1 : (z == 2) ? w2 : w3;
    bf16_t* out = wtout + (size_t)z * RC * RC;
    int c0 = blockIdx.x * 32, r0 = blockIdx.y * 32;
    int tx = threadIdx.x, ty = threadIdx.y;
#pragma unroll
    for (int i = 0; i < 32; i += 8)
        tile[ty + i][tx] = (bf16_t)in[(size_t)(r0 + ty + i) * RC + c0 + tx];
    __syncthreads();
#pragma unroll
    for (int i = 0; i < 32; i += 8)
        out[(size_t)(c0 + ty + i) * RC + r0 + tx] = tile[tx][ty + i];
}

// ===========================================================================
// GEMM core, 128x128 tile, 4 waves (2x2), wave 64x64 via 4x4
// mfma_f32_16x16x32_bf16, BK=64, global_load_lds width-16 into [128][64]
// LDS, 2 buffers, T4 counted-vmcnt pipeline (never vmcnt(0) in steady state).
// T2 both-sides swizzle (r7: conflict 9.5M -> gone; element (row,c) lives at
// phys col c ^ ((row&7)*8); source col pre-inverse-swizzled, read XORs).
// Pipeline: prologue issues tile0->buf0, tile1->buf1; step i: vmcnt(8) ->
// s_barrier -> MFMA -> lgkmcnt(0) -> s_barrier -> issue tile i+2.
// Raw s_barrier, NOT __syncthreads (that drains vmcnt(0) = the stall).
// 64 KB LDS -> 2 blocks/CU.
// Epilogue may reuse smem (32768 elems) as a [128][136] transpose buffer.
// ===========================================================================
#define STAGE_TILE(A_, Wt_, koff, buf)                                        \
    _Pragma("unroll") for (int c = 0; c < 4; c++) {                           \
        int rb = c * 32 + wid * 8;                                            \
        gload16(A_  + arow + (size_t)rb * K + (koff), (buf) + rb * 64);       \
        gload16(Wt_ + brow + (size_t)rb * K + (koff), (buf) + 8192 + rb * 64);\
    }

#define GEMM_CORE(A_, Wt_)                                                    \
    const int K = 1024;                                                       \
    __shared__ __align__(16) bf16_t smem[32768];                              \
    int t = threadIdx.x;                                                      \
    int wid = t >> 6, lane = t & 63, ln = lane & 15, quad = lane >> 4;        \
    int wm = (wid >> 1) * 64, wn = (wid & 1) * 64;                            \
    f32x4 zero = {0.f, 0.f, 0.f, 0.f};                                        \
    f32x4 acc[4][4];                                                          \
    _Pragma("unroll") for (int i = 0; i < 4; i++)                             \
        _Pragma("unroll") for (int j = 0; j < 4; j++) acc[i][j] = zero;       \
    int sr8 = lane >> 3;                                                      \
    int scs = (((lane & 7) ^ sr8) * 8);      /* swizzled source col */        \
    int swr = (ln & 7) * 8;                  /* read-side XOR key   */        \
    const size_t arow = (size_t)(m0 + sr8) * K + scs;                         \
    const size_t brow = (size_t)(n0 + sr8) * K + scs;                         \
    STAGE_TILE(A_, Wt_, 0, smem)                                              \
    STAGE_TILE(A_, Wt_, 64, smem + 16384)                                     \
    for (int it = 0; it < 16; it++) {                                         \
        if (it < 15) asm volatile("s_waitcnt vmcnt(8)" ::: "memory");         \
        else         asm volatile("s_waitcnt vmcnt(0)" ::: "memory");         \
        __builtin_amdgcn_sched_barrier(0);                                    \
        __builtin_amdgcn_s_barrier();                                         \
        bf16_t* a_lds = smem + (it & 1) * 16384;                              \
        bf16_t* b_lds = a_lds + 8192;                                         \
        _Pragma("unroll") for (int ks = 0; ks < 2; ks++) {                    \
            bf16x8 af[4], bfr[4];                                             \
            _Pragma("unroll") for (int i = 0; i < 4; i++)                     \
                af[i] = ld_frag(a_lds + (wm + i * 16 + ln) * 64 +             \
                                ((ks * 32 + quad * 8) ^ swr));                \
            _Pragma("unroll") for (int j = 0; j < 4; j++)                     \
                bfr[j] = ld_frag(b_lds + (wn + j * 16 + ln) * 64 +            \
                                 ((ks * 32 + quad * 8) ^ swr));               \
            _Pragma("unroll") for (int i = 0; i < 4; i++)                     \
                _Pragma("unroll") for (int j = 0; j < 4; j++)                 \
                    acc[i][j] = __builtin_amdgcn_mfma_f32_16x16x32_bf16(      \
                        af[i], bfr[j], acc[i][j], 0, 0, 0);                   \
        }                                                                     \
        asm volatile("s_waitcnt lgkmcnt(0)" ::: "memory");                    \
        __builtin_amdgcn_sched_barrier(0);                                    \
        __builtin_amdgcn_s_barrier();                                        \
        if (it < 14) {                                                        \
            int koff = (it + 2) * 64;                                         \
            bf16_t* bufn = smem + (it & 1) * 16384;                           \
            STAGE_TILE(A_, Wt_, koff, bufn)                                   \
        }                                                                     \
    }

// ---------------------------------------------------------------------------
// Fused QKV projection. grid (24, 32): bx>>3 selects {Q,K,V}, n0=(bx&7)*128.
// Wt buffers contiguous at wtbase (+wsel*1M); outputs contiguous at outbase
// (+wsel*4M). Q,K -> [B,H,S,HD]; V -> [B,H,HD,S] via LDS transpose epilogue.
// Q is PRE-SCALED by 0.125*log2(e) so attn softmax is a single v_exp_f32:
// p = exp2(q_scaled . k) = e^(q.k/8); the old -16 bias cancels in O/l.
// ---------------------------------------------------------------------------
__global__ __launch_bounds__(256) void gemm_qkv(const bf16_t* __restrict__ A,
                                                const bf16_t* __restrict__ wtbase,
                                                bf16_t* __restrict__ outbase) {
    int wsel = blockIdx.x >> 3;
    int n0 = (blockIdx.x & 7) * 128;
    int m0 = blockIdx.y * 128;
    const bf16_t* Wt = wtbase + (size_t)wsel * 1024 * 1024;
    bf16_t* out = outbase + (size_t)wsel * 4 * 1024 * 1024;

    GEMM_CORE(A, Wt)

    if (wsel < 2) {
        float qsc = (wsel == 0) ? 0.18033688f : 1.0f;   // 0.125*log2(e) on Q
        // C[m][n] -> out[b][h][s][hd]  (32-B quad chunks, lines complete in j-loop)
#pragma unroll
        for (int i = 0; i < 4; i++)
#pragma unroll
            for (int j = 0; j < 4; j++) {
                int n = n0 + wn + j * 16 + ln;
                int h = n >> 6, hd = n & 63;
#pragma unroll
                for (int r = 0; r < 4; r++) {
                    int m = m0 + wm + i * 16 + quad * 4 + r;
                    int b = m >> 11, s = m & 2047;
                    out[(((size_t)(b * H_ + h) * S_ + s) * HD_) + hd] =
                        (bf16_t)(acc[i][j][r] * qsc);
                }
            }
    } else {
        // V: transpose C-tile in LDS, then write [b][h][hd][s] coalesced.
        // Loop ended with s_barrier after lgkmcnt(0): smem safely reusable.
        bf16_t* tr = smem;               // [128][136]  (17408 elems, fits)
#pragma unroll
        for (int i = 0; i < 4; i++)
#pragma unroll
            for (int j = 0; j < 4; j++) {
                U16x4 pk;                // acc[i][j][0..3] are consecutive m
#pragma unroll
                for (int r = 0; r < 4; r++) pk.e[r] = (bf16_t)acc[i][j][r];
                *(uint2*)(tr + (wn + j * 16 + ln) * 136 + wm + i * 16 + quad * 4) = pk.u;
            }
        __syncthreads();
        int row = t >> 1, half = t & 1;      // row = n-local, 2 thr/row
        int n = n0 + row;
        int h = n >> 6, hd = n & 63;
        int b = m0 >> 11, s0 = (m0 & 2047) + half * 64;
        const bf16_t* src = tr + row * 136 + half * 64;
        bf16_t* dst = out + (((size_t)(b * H_ + h) * HD_ + hd) * S_) + s0;
#pragma unroll
        for (int u = 0; u < 8; u++)
            *(uint4*)(dst + u * 8) = *(const uint4*)(src + u * 8);
    }
}

// ---------------------------------------------------------------------------
// Output projection: fp32 out[M][N] = ctx @ Wo + bo. grid (8, 32).
// ---------------------------------------------------------------------------
__global__ __launch_bounds__(256) void gemm_out(const bf16_t* __restrict__ A,
                                                const bf16_t* __restrict__ Wt,
                                                float* __restrict__ out,
                                                const float* __restrict__ bias) {
    const int N = 1024;
    int n0 = blockIdx.x * 128;
    int m0 = blockIdx.y * 128;

    GEMM_CORE(A, Wt)

#pragma unroll
    for (int i = 0; i < 4; i++)
#pragma unroll
        for (int j = 0; j < 4; j++) {
            int n = n0 + wn + j * 16 + ln;
            float bv = bias[n];
#pragma unroll
            for (int r = 0; r < 4; r++) {
                int m = m0 + wm + i * 16 + quad * 4 + r;
                out[(size_t)m * N + n] = acc[i][j][r] + bv;
            }
        }
}

// ---------------------------------------------------------------------------
// Causal flash attention (r11 structure, measured 51.6us -- r13's no-LDS
// variant was 3.5x slower: LDS staging IS the coalesce->broadcast converter).
// Softmax: Q pre-scaled by 0.125*log2e in gemm_qkv -> p = exp2(s) via ONE
// v_exp_f32 (bias-free: uniform e^-16 factor cancels in O/l; max p ~ e^16,
// lsum <= 2e10, all safely in fp32/bf16 range).
// Swapped QK^T + zero-shuffle PV (r8): sacc[tt]=mfma(K,Q) -> thread holds
// P[k][q=ln] registers that feed mfma_f32_16x16x16bf16_1k A-operand direct.
// T5 setprio(1) around MFMA clusters (4 independent blocks/CU at different
// phases -> scheduler can favor MFMA-issuing waves; +4-7% per catalog).
//
// v_lds stride 76 (r11 conflict fix); K/V double-buffer, ONE __syncthreads
// per tile. LDS 37.9 KB -> 4 blocks/CU.
// Grid 1024, balance by construction: xcd=bid&7, c=(bid>>3)&31, g=bid>>8;
// bh=xcd+8g (K/V L2-resident per XCD); qt=(g&1)?c:31-c.
// Causal mask only at kt==qt (wave-uniform branch).
// Q,K: [B*H][S][64] ; Vt: [B*H][64][S] ; ctx: [B][S][H*64] bf16
// ---------------------------------------------------------------------------
__global__ __launch_bounds__(256) void attn64(const bf16_t* __restrict__ Q,
                                              const bf16_t* __restrict__ Kg,
                                              const bf16_t* __restrict__ Vt,
                                              bf16_t* __restrict__ ctx) {
    __shared__ __align__(16) bf16_t k_lds[2][64 * 72];
    __shared__ __align__(16) bf16_t v_lds[2][64 * 76];   // [hd][s_local]

    int t = threadIdx.x;
    int wid = t >> 6, lane = t & 63, ln = lane & 15, quad = lane >> 4;

    int bid = blockIdx.x;                        // 1024 blocks
    int xcd = bid & 7;
    int c   = (bid >> 3) & 31;                   // CU-within-XCD (round robin)
    int g   = bid >> 8;                          // resident slot 0..3
    int bh  = xcd + (g << 3);
    int qt  = (g & 1) ? c : (31 - c);
    int b = bh >> 4, h = bh & 15;
    const bf16_t* Qb = Q  + (size_t)bh * S_ * HD_;
    const bf16_t* Kb = Kg + (size_t)bh * S_ * HD_;
    const bf16_t* Vb = Vt + (size_t)bh * HD_ * S_;

    int srow = t >> 2, schunk = t & 3;
    f32x4 zero = {0.f, 0.f, 0.f, 0.f};

    int q0 = qt * 64;
    int nkt = qt + 1;

    int qrow = q0 + wid * 16 + ln;               // this thread's q (col idx)
    bf16x8 qf0 = ld_frag(Qb + (size_t)qrow * HD_ + quad * 8);
    bf16x8 qf1 = ld_frag(Qb + (size_t)qrow * HD_ + 32 + quad * 8);

    f32x4 oacc[4];
#pragma unroll
    for (int i = 0; i < 4; i++) oacc[i] = zero;
    float lsum = 0.f;                            // partial row-sum for q=qrow

    // tile 0: load regs, write buf0, one barrier
    {
        const uint4* ksrc = (const uint4*)(Kb + (size_t)srow * HD_);
        const uint4* vsrc = (const uint4*)(Vb + (size_t)srow * S_);
        uint4 kv0 = ksrc[schunk * 2], kv1 = ksrc[schunk * 2 + 1];
        uint4 vv0 = vsrc[schunk * 2], vv1 = vsrc[schunk * 2 + 1];
        *(uint4*)(k_lds[0] + srow * 72 + schunk * 16)     = kv0;
        *(uint4*)(k_lds[0] + srow * 72 + schunk * 16 + 8) = kv1;
        *(uint4*)(v_lds[0] + srow * 76 + schunk * 16)     = vv0;
        *(uint4*)(v_lds[0] + srow * 76 + schunk * 16 + 8) = vv1;
    }
    __syncthreads();

    for (int kt = 0; kt < nkt; kt++) {
        int cur = kt & 1;
        uint4 kv0, kv1, vv0, vv1;
        bool pf = (kt + 1 < nkt);
        if (pf) {                         // issue next-tile loads (L2) early
            int k0n = (kt + 1) * 64;
            const uint4* ksrc = (const uint4*)(Kb + (size_t)(k0n + srow) * HD_);
            const uint4* vsrc = (const uint4*)(Vb + (size_t)srow * S_ + k0n);
            kv0 = ksrc[schunk * 2]; kv1 = ksrc[schunk * 2 + 1];
            vv0 = vsrc[schunk * 2]; vv1 = vsrc[schunk * 2 + 1];
        }

        const bf16_t* kl = k_lds[cur];
        const bf16_t* vl = v_lds[cur];

        // S^T = K Q^T : sacc[tt][r] = S[k=kt*64+tt*16+quad*4+r][q=qrow]
        f32x4 sacc[4];
#pragma unroll
        for (int tt = 0; tt < 4; tt++) sacc[tt] = zero;
        __builtin_amdgcn_s_setprio(1);
#pragma unroll
        for (int tt = 0; tt < 4; tt++) {
            bf16x8 a0 = ld_frag(kl + (tt * 16 + ln) * 72 + quad * 8);
            bf16x8 a1 = ld_frag(kl + (tt * 16 + ln) * 72 + 32 + quad * 8);
            sacc[tt] = __builtin_amdgcn_mfma_f32_16x16x32_bf16(a0, qf0, sacc[tt], 0, 0, 0);
            sacc[tt] = __builtin_amdgcn_mfma_f32_16x16x32_bf16(a1, qf1, sacc[tt], 0, 0, 0);
        }
        __builtin_amdgcn_s_setprio(0);

        U16x4s pa[4];
        if (kt == nkt - 1) {              // diagonal tile: mask k > q
#pragma unroll
            for (int tt = 0; tt < 4; tt++) {
#pragma unroll
                for (int r = 0; r < 4; r++) {
                    int kg = kt * 64 + tt * 16 + quad * 4 + r;
                    float pv = __builtin_exp2f((float)sacc[tt][r]);
                    if (kg > qrow) pv = 0.f;
                    lsum += pv;
                    pa[tt].e[r] = (bf16_t)pv;
                }
            }
        } else {                          // interior tile: no mask
#pragma unroll
            for (int tt = 0; tt < 4; tt++) {
#pragma unroll
                for (int r = 0; r < 4; r++) {
                    float pv = __builtin_exp2f((float)sacc[tt][r]);
                    lsum += pv;
                    pa[tt].e[r] = (bf16_t)pv;
                }
            }
        }

        // PV: P registers feed 16x16x16 MFMA A-operand directly.
        __builtin_amdgcn_s_setprio(1);
#pragma unroll
        for (int th = 0; th < 4; th++) {
#pragma unroll
            for (int tt = 0; tt < 4; tt++) {
                U16x4s vb;
                vb.u = *(const uint2*)(vl + (th * 16 + ln) * 76 +
                                       tt * 16 + quad * 4);
                oacc[th] = __builtin_amdgcn_mfma_f32_16x16x16bf16_1k(
                    pa[tt].s, vb.s, oacc[th], 0, 0, 0);
            }
        }
        __builtin_amdgcn_s_setprio(0);

        if (pf) {                         // write next tile into other buffer
            bf16_t* kn = k_lds[cur ^ 1];
            bf16_t* vn = v_lds[cur ^ 1];
            *(uint4*)(kn + srow * 72 + schunk * 16)     = kv0;
            *(uint4*)(kn + srow * 72 + schunk * 16 + 8) = kv1;
            *(uint4*)(vn + srow * 76 + schunk * 16)     = vv0;
            *(uint4*)(vn + srow * 76 + schunk * 16 + 8) = vv1;
        }
        __syncthreads();                  // writes visible; reads of cur done
    }

    // l totals: sum the 4 quad-partials for each q=ln
    lsum += __shfl_xor(lsum, 16);
    lsum += __shfl_xor(lsum, 32);

#pragma unroll
    for (int r = 0; r < 4; r++) {
        int q = q0 + wid * 16 + quad * 4 + r;
        float inv = 1.f / __shfl(lsum, quad * 4 + r);  // lane q-local
#pragma unroll
        for (int th = 0; th < 4; th++) {
            int hd = h * 64 + th * 16 + ln;
            ctx[((size_t)(b * S_ + q)) * D_ + hd] = (bf16_t)(oacc[th][r] * inv);
        }
    }
}

// ---------------------------------------------------------------------------
extern "C" void kernel_launch(void* const* d_in, const int* in_sizes, int n_in,
                              void* d_out, int out_size, void* d_ws, size_t ws_size,
                              hipStream_t stream) {
    const float* x  = (const float*)d_in[0];
    const float* bo = (const float*)d_in[5];
    float* out = (float*)d_out;

    bf16_t* ws = (bf16_t*)d_ws;
    const size_t MM = 1024 * 1024;       // elements
    bf16_t* xb  = ws;                    // [M][D]  4 MM  (dead after QKV gemm)
    bf16_t* ctx = xb;                    //   alias — lifetimes disjoint
    bf16_t* wtq = xb + 4 * MM;           // [N][K]  1 MM each (q,k,v,o contig)
    bf16_t* wto = wtq + 3 * MM;
    bf16_t* qb  = wto + MM;              // [B,H,S,HD] 4 MM (q,k,vT contig)
    bf16_t* kb  = qb + 4 * MM;
    bf16_t* vtb = kb + 4 * MM;           // [B,H,HD,S]
    // total 20 MM elems = 40 MB

    ingest<<<dim3(32, 32, 5), dim3(32, 8, 1), 0, stream>>>(
        (const float*)d_in[1], (const float*)d_in[2],
        (const float*)d_in[3], (const float*)d_in[4], x, wtq, xb);

    gemm_qkv<<<dim3(24, 32, 1), 256, 0, stream>>>(xb, wtq, qb);

    attn64<<<1024, 256, 0, stream>>>(qb, kb, vtb, ctx);

    gemm_out<<<dim3(8, 32, 1), 256, 0, stream>>>(ctx, wto, out, bo);
}

// Round 15
// 191.669 us; speedup vs baseline: 1.6890x; 1.0196x over previous
//
#include <hip/hip_runtime.h>

#define B_  2
#define S_  2048
#define D_  1024
#define H_  16
#define HD_ 64
#define M_  (B_*S_)   // 4096 tokens

typedef __bf16 bf16_t;
typedef __bf16 bf16x8 __attribute__((ext_vector_type(8)));
typedef float  f32x4  __attribute__((ext_vector_type(4)));
typedef short  s16x4  __attribute__((ext_vector_type(4)));

union U16x8 { uint4 u; bf16x8 v; };
union U16x4 { uint2 u; bf16_t e[4]; };
union U16x4s { uint2 u; s16x4 s; bf16_t e[4]; };

__device__ __forceinline__ bf16x8 ld_frag(const bf16_t* p) {
    U16x8 t; t.u = *(const uint4*)p; return t.v;
}

// async global->LDS DMA, 16 B per lane. LDS dest must be wave-uniform base;
// HW adds lane*16. Global src is per-lane.
__device__ __forceinline__ void gload16(const bf16_t* g, bf16_t* l) {
    __builtin_amdgcn_global_load_lds(
        (const __attribute__((address_space(1))) unsigned int*)g,
        (__attribute__((address_space(3))) unsigned int*)l,
        16, 0, 0);
}

// ---------------------------------------------------------------------------
// Ingestion, one launch. grid (32,32,5), block (32,8):
//   z<4 : weight fp32 [1024][1024] -> bf16 transposed [n][k] (z selects W)
//   z==4: x fp32 -> bf16, 16 elems/thread (1024 block-slots x 4096 elems)
// ---------------------------------------------------------------------------
__global__ __launch_bounds__(256) void ingest(const float* __restrict__ w0,
                                              const float* __restrict__ w1,
                                              const float* __restrict__ w2,
                                              const float* __restrict__ w3,
                                              const float* __restrict__ xin,
                                              bf16_t* __restrict__ wtout,
                                              bf16_t* __restrict__ xout) {
    const int RC = 1024;
    int z = blockIdx.z;
    if (z == 4) {
        int bid = blockIdx.y * 32 + blockIdx.x;
        int t = threadIdx.y * 32 + threadIdx.x;
        int i = bid * 4096 + t * 16;
#pragma unroll
        for (int g = 0; g < 2; g++) {
            float4 a = *(const float4*)(xin + i + g * 8);
            float4 b = *(const float4*)(xin + i + g * 8 + 4);
            bf16_t o[8] = {(bf16_t)a.x, (bf16_t)a.y, (bf16_t)a.z, (bf16_t)a.w,
                           (bf16_t)b.x, (bf16_t)b.y, (bf16_t)b.z, (bf16_t)b.w};
            *(uint4*)(xout + i + g * 8) = *(uint4*)o;
        }
        return;
    }
    __shared__ bf16_t tile[32][33];
    const float* in = (z == 0) ? w0 : (z == 1) ? w1 : (z == 2) ? w2 : w3;
    bf16_t* out = wtout + (size_t)z * RC * RC;
    int c0 = blockIdx.x * 32, r0 = blockIdx.y * 32;
    int tx = threadIdx.x, ty = threadIdx.y;
#pragma unroll
    for (int i = 0; i < 32; i += 8)
        tile[ty + i][tx] = (bf16_t)in[(size_t)(r0 + ty + i) * RC + c0 + tx];
    __syncthreads();
#pragma unroll
    for (int i = 0; i < 32; i += 8)
        out[(size_t)(c0 + ty + i) * RC + r0 + tx] = tile[tx][ty + i];
}

// ===========================================================================
// GEMM core, 128x128 tile, 4 waves (2x2), wave 64x64 via 4x4
// mfma_f32_16x16x32_bf16, BK=64, global_load_lds width-16 into [128][64]
// LDS, 2 buffers, T4 counted-vmcnt pipeline (never vmcnt(0) in steady state).
// T2 both-sides swizzle (r7: conflict 9.5M -> gone; element (row,c) lives at
// phys col c ^ ((row&7)*8); source col pre-inverse-swizzled, read XORs).
// Pipeline: prologue issues tile0->buf0, tile1->buf1; step i: vmcnt(8) ->
// s_barrier -> MFMA -> lgkmcnt(0) -> s_barrier -> issue tile i+2.
// Raw s_barrier, NOT __syncthreads (that drains vmcnt(0) = the stall).
// 64 KB LDS -> 2 blocks/CU.
// Epilogue may reuse smem (32768 elems) as a [128][136] transpose buffer.
// ===========================================================================
#define STAGE_TILE(A_, Wt_, koff, buf)                                        \
    _Pragma("unroll") for (int c = 0; c < 4; c++) {                           \
        int rb = c * 32 + wid * 8;                                            \
        gload16(A_  + arow + (size_t)rb * K + (koff), (buf) + rb * 64);       \
        gload16(Wt_ + brow + (size_t)rb * K + (koff), (buf) + 8192 + rb * 64);\
    }

#define GEMM_CORE(A_, Wt_)                                                    \
    const int K = 1024;                                                       \
    __shared__ __align__(16) bf16_t smem[32768];                              \
    int t = threadIdx.x;                                                      \
    int wid = t >> 6, lane = t & 63, ln = lane & 15, quad = lane >> 4;        \
    int wm = (wid >> 1) * 64, wn = (wid & 1) * 64;                            \
    f32x4 zero = {0.f, 0.f, 0.f, 0.f};                                        \
    f32x4 acc[4][4];                                                          \
    _Pragma("unroll") for (int i = 0; i < 4; i++)                             \
        _Pragma("unroll") for (int j = 0; j < 4; j++) acc[i][j] = zero;       \
    int sr8 = lane >> 3;                                                      \
    int scs = (((lane & 7) ^ sr8) * 8);      /* swizzled source col */        \
    int swr = (ln & 7) * 8;                  /* read-side XOR key   */        \
    const size_t arow = (size_t)(m0 + sr8) * K + scs;                         \
    const size_t brow = (size_t)(n0 + sr8) * K + scs;                         \
    STAGE_TILE(A_, Wt_, 0, smem)                                              \
    STAGE_TILE(A_, Wt_, 64, smem + 16384)                                     \
    for (int it = 0; it < 16; it++) {                                         \
        if (it < 15) asm volatile("s_waitcnt vmcnt(8)" ::: "memory");         \
        else         asm volatile("s_waitcnt vmcnt(0)" ::: "memory");         \
        __builtin_amdgcn_sched_barrier(0);                                    \
        __builtin_amdgcn_s_barrier();                                         \
        bf16_t* a_lds = smem + (it & 1) * 16384;                              \
        bf16_t* b_lds = a_lds + 8192;                                         \
        _Pragma("unroll") for (int ks = 0; ks < 2; ks++) {                    \
            bf16x8 af[4], bfr[4];                                             \
            _Pragma("unroll") for (int i = 0; i < 4; i++)                     \
                af[i] = ld_frag(a_lds + (wm + i * 16 + ln) * 64 +             \
                                ((ks * 32 + quad * 8) ^ swr));                \
            _Pragma("unroll") for (int j = 0; j < 4; j++)                     \
                bfr[j] = ld_frag(b_lds + (wn + j * 16 + ln) * 64 +            \
                                 ((ks * 32 + quad * 8) ^ swr));               \
            _Pragma("unroll") for (int i = 0; i < 4; i++)                     \
                _Pragma("unroll") for (int j = 0; j < 4; j++)                 \
                    acc[i][j] = __builtin_amdgcn_mfma_f32_16x16x32_bf16(      \
                        af[i], bfr[j], acc[i][j], 0, 0, 0);                   \
        }                                                                     \
        asm volatile("s_waitcnt lgkmcnt(0)" ::: "memory");                    \
        __builtin_amdgcn_sched_barrier(0);                                    \
        __builtin_amdgcn_s_barrier();                                        \
        if (it < 14) {                                                        \
            int koff = (it + 2) * 64;                                         \
            bf16_t* bufn = smem + (it & 1) * 16384;                           \
            STAGE_TILE(A_, Wt_, koff, bufn)                                   \
        }                                                                     \
    }

// ---------------------------------------------------------------------------
// Fused QKV projection, PERSISTENT grid of 512 blocks (r15): 768 tiles at
// 2 blocks/CU capacity (512) previously dispatched as a full round + a
// half-empty round (makespan 2T vs ideal 1.5T). Now block bid does tile
// bid and (bid<256) tile bid+512. Under the verified dispatch model
// (xcd=bid&7, CU=(bid>>3)&31, slot=bid>>8) each CU hosts bid and bid+256:
// one 2-tile + one 1-tile block = exactly 3 tiles/CU.
// Tile tid: wsel=tid>>8 selects {Q,K,V}; rem=tid&255: m0=(rem>>3)*128,
// n0=(rem&7)*128. Q,K -> [B,H,S,HD]; V -> [B,H,HD,S] via LDS transpose.
// Rep-boundary __syncthreads() (drains vmcnt+lgkm) makes smem reuse safe.
// ---------------------------------------------------------------------------
__global__ __launch_bounds__(256) void gemm_qkv(const bf16_t* __restrict__ A,
                                                const bf16_t* __restrict__ wtbase,
                                                bf16_t* __restrict__ outbase) {
#pragma unroll 1
    for (int rep = 0; rep < 2; rep++) {
        int tid = (int)blockIdx.x + rep * 512;
        if (tid >= 768) break;
        int wsel = tid >> 8;
        int rem  = tid & 255;
        int m0 = (rem >> 3) * 128;
        int n0 = (rem & 7) * 128;
        const bf16_t* Wt = wtbase + (size_t)wsel * 1024 * 1024;
        bf16_t* out = outbase + (size_t)wsel * 4 * 1024 * 1024;
        if (rep) __syncthreads();        // all waves done with rep-0 smem

        GEMM_CORE(A, Wt)

        if (wsel < 2) {
            // C[m][n] -> out[b][h][s][hd]  (32-B quad chunks)
#pragma unroll
            for (int i = 0; i < 4; i++)
#pragma unroll
                for (int j = 0; j < 4; j++) {
                    int n = n0 + wn + j * 16 + ln;
                    int h = n >> 6, hd = n & 63;
#pragma unroll
                    for (int r = 0; r < 4; r++) {
                        int m = m0 + wm + i * 16 + quad * 4 + r;
                        int b = m >> 11, s = m & 2047;
                        out[(((size_t)(b * H_ + h) * S_ + s) * HD_) + hd] =
                            (bf16_t)acc[i][j][r];
                    }
                }
        } else {
            // V: transpose C-tile in LDS, then write [b][h][hd][s] coalesced.
            // Loop ended with s_barrier after lgkmcnt(0): smem reusable.
            bf16_t* tr = smem;           // [128][136]  (17408 elems, fits)
#pragma unroll
            for (int i = 0; i < 4; i++)
#pragma unroll
                for (int j = 0; j < 4; j++) {
                    U16x4 pk;            // acc[i][j][0..3] are consecutive m
#pragma unroll
                    for (int r = 0; r < 4; r++) pk.e[r] = (bf16_t)acc[i][j][r];
                    *(uint2*)(tr + (wn + j * 16 + ln) * 136 + wm + i * 16 + quad * 4) = pk.u;
                }
            __syncthreads();
            int row = t >> 1, half = t & 1;  // row = n-local, 2 thr/row
            int n = n0 + row;
            int h = n >> 6, hd = n & 63;
            int b = m0 >> 11, s0 = (m0 & 2047) + half * 64;
            const bf16_t* src = tr + row * 136 + half * 64;
            bf16_t* dst = out + (((size_t)(b * H_ + h) * HD_ + hd) * S_) + s0;
#pragma unroll
            for (int u = 0; u < 8; u++)
                *(uint4*)(dst + u * 8) = *(const uint4*)(src + u * 8);
        }
    }
}

// ---------------------------------------------------------------------------
// Output projection: fp32 out[M][N] = ctx @ Wo + bo. grid (8, 32).
// ---------------------------------------------------------------------------
__global__ __launch_bounds__(256) void gemm_out(const bf16_t* __restrict__ A,
                                                const bf16_t* __restrict__ Wt,
                                                float* __restrict__ out,
                                                const float* __restrict__ bias) {
    const int N = 1024;
    int n0 = blockIdx.x * 128;
    int m0 = blockIdx.y * 128;

    GEMM_CORE(A, Wt)

#pragma unroll
    for (int i = 0; i < 4; i++)
#pragma unroll
        for (int j = 0; j < 4; j++) {
            int n = n0 + wn + j * 16 + ln;
            float bv = bias[n];
#pragma unroll
            for (int r = 0; r < 4; r++) {
                int m = m0 + wm + i * 16 + quad * 4 + r;
                out[(size_t)m * N + n] = acc[i][j][r] + bv;
            }
        }
}

// ---------------------------------------------------------------------------
// Causal flash attention -- EXACT r11 structure (measured 51.6 us; r14's
// exp2-builtin raised VALUBusy via denormal-guard lowering and setprio is
// null-to-negative on 4-wave-lockstep blocks -- both reverted).
// Static-max softmax: p = exp(s/8 - 16); l deferred; O/l at epilogue.
// Swapped QK^T + zero-shuffle PV (r8): sacc[tt]=mfma(K,Q) -> thread holds
// P[k][q=ln] registers that feed mfma_f32_16x16x16bf16_1k A-operand direct.
// v_lds stride 76 (r11 conflict fix: 6.5M->2.2M cycles); K/V double-buffer,
// ONE __syncthreads per tile. LDS 37.9 KB -> 4 blocks/CU.
// Grid 1024, balance by construction: xcd=bid&7, c=(bid>>3)&31, g=bid>>8;
// bh=xcd+8g (K/V L2-resident per XCD); qt=(g&1)?c:31-c (every CU's 4
// resident blocks sum to 66 KV-tile units).
// Causal mask only at kt==qt (wave-uniform branch).
// Q,K: [B*H][S][64] ; Vt: [B*H][64][S] ; ctx: [B][S][H*64] bf16
// ---------------------------------------------------------------------------
__global__ __launch_bounds__(256) void attn64(const bf16_t* __restrict__ Q,
                                              const bf16_t* __restrict__ Kg,
                                              const bf16_t* __restrict__ Vt,
                                              bf16_t* __restrict__ ctx) {
    __shared__ __align__(16) bf16_t k_lds[2][64 * 72];
    __shared__ __align__(16) bf16_t v_lds[2][64 * 76];   // [hd][s_local]

    int t = threadIdx.x;
    int wid = t >> 6, lane = t & 63, ln = lane & 15, quad = lane >> 4;

    int bid = blockIdx.x;                        // 1024 blocks
    int xcd = bid & 7;
    int c   = (bid >> 3) & 31;                   // CU-within-XCD (round robin)
    int g   = bid >> 8;                          // resident slot 0..3
    int bh  = xcd + (g << 3);
    int qt  = (g & 1) ? c : (31 - c);
    int b = bh >> 4, h = bh & 15;
    const bf16_t* Qb = Q  + (size_t)bh * S_ * HD_;
    const bf16_t* Kb = Kg + (size_t)bh * S_ * HD_;
    const bf16_t* Vb = Vt + (size_t)bh * HD_ * S_;

    int srow = t >> 2, schunk = t & 3;
    f32x4 zero = {0.f, 0.f, 0.f, 0.f};

    int q0 = qt * 64;
    int nkt = qt + 1;

    int qrow = q0 + wid * 16 + ln;               // this thread's q (col idx)
    bf16x8 qf0 = ld_frag(Qb + (size_t)qrow * HD_ + quad * 8);
    bf16x8 qf1 = ld_frag(Qb + (size_t)qrow * HD_ + 32 + quad * 8);

    f32x4 oacc[4];
#pragma unroll
    for (int i = 0; i < 4; i++) oacc[i] = zero;
    float lsum = 0.f;                            // partial row-sum for q=qrow

    // tile 0: load regs, write buf0, one barrier
    {
        const uint4* ksrc = (const uint4*)(Kb + (size_t)srow * HD_);
        const uint4* vsrc = (const uint4*)(Vb + (size_t)srow * S_);
        uint4 kv0 = ksrc[schunk * 2], kv1 = ksrc[schunk * 2 + 1];
        uint4 vv0 = vsrc[schunk * 2], vv1 = vsrc[schunk * 2 + 1];
        *(uint4*)(k_lds[0] + srow * 72 + schunk * 16)     = kv0;
        *(uint4*)(k_lds[0] + srow * 72 + schunk * 16 + 8) = kv1;
        *(uint4*)(v_lds[0] + srow * 76 + schunk * 16)     = vv0;
        *(uint4*)(v_lds[0] + srow * 76 + schunk * 16 + 8) = vv1;
    }
    __syncthreads();

    for (int kt = 0; kt < nkt; kt++) {
        int cur = kt & 1;
        uint4 kv0, kv1, vv0, vv1;
        bool pf = (kt + 1 < nkt);
        if (pf) {                         // issue next-tile loads (L2) early
            int k0n = (kt + 1) * 64;
            const uint4* ksrc = (const uint4*)(Kb + (size_t)(k0n + srow) * HD_);
            const uint4* vsrc = (const uint4*)(Vb + (size_t)srow * S_ + k0n);
            kv0 = ksrc[schunk * 2]; kv1 = ksrc[schunk * 2 + 1];
            vv0 = vsrc[schunk * 2]; vv1 = vsrc[schunk * 2 + 1];
        }

        const bf16_t* kl = k_lds[cur];
        const bf16_t* vl = v_lds[cur];

        // S^T = K Q^T : sacc[tt][r] = S[k=kt*64+tt*16+quad*4+r][q=qrow]
        f32x4 sacc[4];
#pragma unroll
        for (int tt = 0; tt < 4; tt++) sacc[tt] = zero;
#pragma unroll
        for (int tt = 0; tt < 4; tt++) {
            bf16x8 a0 = ld_frag(kl + (tt * 16 + ln) * 72 + quad * 8);
            bf16x8 a1 = ld_frag(kl + (tt * 16 + ln) * 72 + 32 + quad * 8);
            sacc[tt] = __builtin_amdgcn_mfma_f32_16x16x32_bf16(a0, qf0, sacc[tt], 0, 0, 0);
            sacc[tt] = __builtin_amdgcn_mfma_f32_16x16x32_bf16(a1, qf1, sacc[tt], 0, 0, 0);
        }

        U16x4s pa[4];
        if (kt == nkt - 1) {              // diagonal tile: mask k > q
#pragma unroll
            for (int tt = 0; tt < 4; tt++) {
#pragma unroll
                for (int r = 0; r < 4; r++) {
                    int kg = kt * 64 + tt * 16 + quad * 4 + r;
                    float pv = __expf(__builtin_fmaf((float)sacc[tt][r], 0.125f, -16.0f));
                    if (kg > qrow) pv = 0.f;
                    lsum += pv;
                    pa[tt].e[r] = (bf16_t)pv;
                }
            }
        } else {                          // interior tile: no mask
#pragma unroll
            for (int tt = 0; tt < 4; tt++) {
#pragma unroll
                for (int r = 0; r < 4; r++) {
                    float pv = __expf(__builtin_fmaf((float)sacc[tt][r], 0.125f, -16.0f));
                    lsum += pv;
                    pa[tt].e[r] = (bf16_t)pv;
                }
            }
        }

        // PV: P registers feed 16x16x16 MFMA A-operand directly.
#pragma unroll
        for (int th = 0; th < 4; th++) {
#pragma unroll
            for (int tt = 0; tt < 4; tt++) {
                U16x4s vb;
                vb.u = *(const uint2*)(vl + (th * 16 + ln) * 76 +
                                       tt * 16 + quad * 4);
                oacc[th] = __builtin_amdgcn_mfma_f32_16x16x16bf16_1k(
                    pa[tt].s, vb.s, oacc[th], 0, 0, 0);
            }
        }

        if (pf) {                         // write next tile into other buffer
            bf16_t* kn = k_lds[cur ^ 1];
            bf16_t* vn = v_lds[cur ^ 1];
            *(uint4*)(kn + srow * 72 + schunk * 16)     = kv0;
            *(uint4*)(kn + srow * 72 + schunk * 16 + 8) = kv1;
            *(uint4*)(vn + srow * 76 + schunk * 16)     = vv0;
            *(uint4*)(vn + srow * 76 + schunk * 16 + 8) = vv1;
        }
        __syncthreads();                  // writes visible; reads of cur done
    }

    // l totals: sum the 4 quad-partials for each q=ln
    lsum += __shfl_xor(lsum, 16);
    lsum += __shfl_xor(lsum, 32);

#pragma unroll
    for (int r = 0; r < 4; r++) {
        int q = q0 + wid * 16 + quad * 4 + r;
        float inv = 1.f / __shfl(lsum, quad * 4 + r);  // lane q-local
#pragma unroll
        for (int th = 0; th < 4; th++) {
            int hd = h * 64 + th * 16 + ln;
            ctx[((size_t)(b * S_ + q)) * D_ + hd] = (bf16_t)(oacc[th][r] * inv);
        }
    }
}

// ---------------------------------------------------------------------------
extern "C" void kernel_launch(void* const* d_in, const int* in_sizes, int n_in,
                              void* d_out, int out_size, void* d_ws, size_t ws_size,
                              hipStream_t stream) {
    const float* x  = (const float*)d_in[0];
    const float* bo = (const float*)d_in[5];
    float* out = (float*)d_out;

    bf16_t* ws = (bf16_t*)d_ws;
    const size_t MM = 1024 * 1024;       // elements
    bf16_t* xb  = ws;                    // [M][D]  4 MM  (dead after QKV gemm)
    bf16_t* ctx = xb;                    //   alias — lifetimes disjoint
    bf16_t* wtq = xb + 4 * MM;           // [N][K]  1 MM each (q,k,v,o contig)
    bf16_t* wto = wtq + 3 * MM;
    bf16_t* qb  = wto + MM;              // [B,H,S,HD] 4 MM (q,k,vT contig)
    bf16_t* kb  = qb + 4 * MM;
    bf16_t* vtb = kb + 4 * MM;           // [B,H,HD,S]
    // total 20 MM elems = 40 MB

    ingest<<<dim3(32, 32, 5), dim3(32, 8, 1), 0, stream>>>(
        (const float*)d_in[1], (const float*)d_in[2],
        (const float*)d_in[3], (const float*)d_in[4], x, wtq, xb);

    gemm_qkv<<<512, 256, 0, stream>>>(xb, wtq, qb);

    attn64<<<1024, 256, 0, stream>>>(qb, kb, vtb, ctx);

    gemm_out<<<dim3(8, 32, 1), 256, 0, stream>>>(ctx, wto, out, bo);
}